// Round 3
// baseline (3348.080 us; speedup 1.0000x reference)
//
#include <hip/hip_runtime.h>
#include <hip/hip_bf16.h>

// GCN encoder: conv1(512->256) -> BN -> ReLU -> conv2(256->128) -> BN
// R3: bucket-sorted adjacency (8 src-range buckets of 6250 nodes) so the
// gather working set per phase is 3.2 MB (fits per-XCD L2). One wave owns
// 16 nodes with fp32 register accumulators; all waves co-resident walk
// buckets in the same order -> natural lockstep -> L2-hit gathers.

#define NN 50000
#define NE 1600000
#define DIN 512
#define D1 256
#define D2 128
#define EPSV 1e-5f
#define NBUCK 8
#define BSZ 6250  // nodes per bucket

typedef __attribute__((ext_vector_type(8))) short bf16x8_t;
typedef __attribute__((ext_vector_type(4))) float f32x4_t;

__device__ __forceinline__ float bf2f(unsigned short u) {
  return __uint_as_float(((unsigned int)u) << 16);
}
__device__ __forceinline__ unsigned short f2bf(float f) {
  unsigned int u = __float_as_uint(f);
  u += 0x7fffu + ((u >> 16) & 1u);   // RNE
  return (unsigned short)(u >> 16);
}
__device__ __forceinline__ unsigned int pk2(float a, float b) {
  __hip_bfloat162 h = __float22bfloat162_rn(make_float2(a, b));
  union { __hip_bfloat162 h; unsigned int u; } c;
  c.h = h;
  return c.u;
}

// ---------- CSR build (bucketed) ----------
__global__ void k_zero(int* __restrict__ cnt, int* __restrict__ cnt2,
                       float* __restrict__ stats) {
  int i = blockIdx.x * blockDim.x + threadIdx.x;
  if (i < NN) cnt[i] = 0;
  if (i < NN * NBUCK) cnt2[i] = 0;
  if (i < (D1 * 2 + D2 * 2)) stats[i] = 0.0f;
}

__global__ void k_hist(const int* __restrict__ src, const int* __restrict__ dst,
                       int* __restrict__ cnt, int* __restrict__ cnt2) {
  int e = blockIdx.x * blockDim.x + threadIdx.x;
  if (e < NE) {
    int d = dst[e];
    int b = (unsigned)src[e] / BSZ;
    atomicAdd(&cnt[d], 1);
    atomicAdd(&cnt2[d * NBUCK + b], 1);
  }
}

__global__ void k_scan_partial(const int* __restrict__ cnt, int* __restrict__ part) {
  __shared__ int s[256];
  int t = threadIdx.x;
  int i = blockIdx.x * 256 + t;
  s[t] = (i < NN) ? cnt[i] : 0;
  __syncthreads();
  for (int off = 128; off > 0; off >>= 1) {
    if (t < off) s[t] += s[t + off];
    __syncthreads();
  }
  if (t == 0) part[blockIdx.x] = s[0];
}

__global__ void k_scan_block(int* __restrict__ part, int nb) {
  __shared__ int s[256];
  int t = threadIdx.x;
  int v = (t < nb) ? part[t] : 0;
  s[t] = v;
  __syncthreads();
  for (int off = 1; off < 256; off <<= 1) {
    int add = (t >= off) ? s[t - off] : 0;
    __syncthreads();
    s[t] += add;
    __syncthreads();
  }
  part[t] = s[t] - v;  // exclusive block offsets
}

__global__ void k_scan_final(const int* __restrict__ cnt, const int* __restrict__ boff,
                             int* __restrict__ row_ptr, float* __restrict__ dis) {
  __shared__ int s[256];
  int t = threadIdx.x;
  int i = blockIdx.x * 256 + t;
  int v = (i < NN) ? cnt[i] : 0;
  s[t] = v;
  __syncthreads();
  for (int off = 1; off < 256; off <<= 1) {
    int add = (t >= off) ? s[t - off] : 0;
    __syncthreads();
    s[t] += add;
    __syncthreads();
  }
  if (i < NN) {
    int excl = boff[blockIdx.x] + s[t] - v;
    row_ptr[i] = excl;
    dis[i] = rsqrtf((float)(v + 1));  // self-loop guarantees deg>=1
    if (i == NN - 1) row_ptr[NN] = excl + v;
  }
}

// per-node bucket starts; cnt2 becomes the fill cursor (in place)
__global__ void k_brow(const int* __restrict__ row_ptr, int* __restrict__ cnt2,
                       int* __restrict__ bptr9) {
  int n = blockIdx.x * 256 + threadIdx.x;
  if (n < NN) {
    int base = row_ptr[n];
#pragma unroll
    for (int b = 0; b < NBUCK; b++) {
      int c = cnt2[n * NBUCK + b];
      bptr9[n * 9 + b] = base;
      cnt2[n * NBUCK + b] = base;  // cursor
      base += c;
    }
    bptr9[n * 9 + 8] = base;
  }
}

__global__ void k_fill(const int* __restrict__ src, const int* __restrict__ dst,
                       int* __restrict__ cnt2, int* __restrict__ col) {
  int e = blockIdx.x * blockDim.x + threadIdx.x;
  if (e < NE) {
    int s = src[e], d = dst[e];
    int b = (unsigned)s / BSZ;
    int pos = atomicAdd(&cnt2[d * NBUCK + b], 1);
    col[pos] = s;
  }
}

// ---------- weight prep: W [KxN] fp32 -> Wt [NxK] bf16 ----------
__global__ void k_prep_w(const float* __restrict__ W1, const float* __restrict__ W2,
                         unsigned short* __restrict__ W1t, unsigned short* __restrict__ W2t) {
  int i = blockIdx.x * 256 + threadIdx.x;
  if (i < DIN * D1) {  // W1t[n*DIN + k] = W1[k*D1 + n]
    int n = i / DIN, k = i - n * DIN;
    W1t[i] = f2bf(W1[(size_t)k * D1 + n]);
  } else {
    int j = i - DIN * D1;  // W2t[n*D1 + k] = W2[k*D2 + n]
    int n = j / D1, k = j - n * D1;
    W2t[j] = f2bf(W2[(size_t)k * D2 + n]);
  }
}

// ---------- MFMA GEMM: C[MxN] bf16 = A[MxK] @ Bt[NxK]^T, fp32 accum ----------
template <int K, bool A_IS_F32>
__global__ __launch_bounds__(256) void k_gemm_mfma(const void* __restrict__ Ap,
                                                   const unsigned short* __restrict__ Bt,
                                                   unsigned short* __restrict__ C,
                                                   int M, int N) {
  __shared__ unsigned short As[128 * 64];
  __shared__ unsigned short Bs[128 * 64];
  const int t = threadIdx.x;
  const int wave = t >> 6, lane = t & 63;
  const int m0 = blockIdx.x * 128, n0 = blockIdx.y * 128;
  const int wm = (wave >> 1) * 64, wn = (wave & 1) * 64;
  const int l8 = lane >> 3;
  const int lbs = (lane & 7) ^ l8;  // logical k-block for staging
  const int row_c = lane & 15, quad = lane >> 4;

  f32x4_t acc[4][4];
#pragma unroll
  for (int i = 0; i < 4; i++)
#pragma unroll
    for (int j = 0; j < 4; j++) acc[i][j] = (f32x4_t){0.f, 0.f, 0.f, 0.f};

  for (int k0 = 0; k0 < K; k0 += 64) {
#pragma unroll
    for (int j = 0; j < 4; j++) {
      int chunk = wave * 4 + j;
      int row = chunk * 8 + l8;
      const unsigned short* g = Bt + (size_t)(n0 + row) * K + k0 + lbs * 8;
      __builtin_amdgcn_global_load_lds(
          (const __attribute__((address_space(1))) unsigned int*)g,
          (__attribute__((address_space(3))) unsigned int*)(Bs + chunk * 512), 16, 0, 0);
    }
    if (A_IS_F32) {
      const float* A = (const float*)Ap;
#pragma unroll
      for (int i = 0; i < 4; i++) {
        int bid = i * 256 + t;
        int row = bid >> 3, pb = bid & 7;
        int lb = pb ^ (row & 7);
        int gm = m0 + row;
        if (gm >= M) gm = M - 1;
        const float4* s = (const float4*)(A + (size_t)gm * K + k0 + lb * 8);
        float4 v0 = s[0], v1 = s[1];
        uint4 o;
        o.x = pk2(v0.x, v0.y);
        o.y = pk2(v0.z, v0.w);
        o.z = pk2(v1.x, v1.y);
        o.w = pk2(v1.z, v1.w);
        *(uint4*)(As + row * 64 + pb * 8) = o;
      }
    } else {
      const unsigned short* A = (const unsigned short*)Ap;
#pragma unroll
      for (int j = 0; j < 4; j++) {
        int chunk = wave * 4 + j;
        int row = chunk * 8 + l8;
        int gm = m0 + row;
        if (gm >= M) gm = M - 1;
        const unsigned short* g = A + (size_t)gm * K + k0 + lbs * 8;
        __builtin_amdgcn_global_load_lds(
            (const __attribute__((address_space(1))) unsigned int*)g,
            (__attribute__((address_space(3))) unsigned int*)(As + chunk * 512), 16, 0, 0);
      }
    }
    __syncthreads();
#pragma unroll
    for (int ki = 0; ki < 2; ki++) {
      bf16x8_t af[4], bfr[4];
      int kb = ki * 4 + quad;
#pragma unroll
      for (int i = 0; i < 4; i++) {
        int ar = wm + i * 16 + row_c;
        af[i] = *(const bf16x8_t*)(As + ar * 64 + ((kb ^ (ar & 7)) * 8));
        int br = wn + i * 16 + row_c;
        bfr[i] = *(const bf16x8_t*)(Bs + br * 64 + ((kb ^ (br & 7)) * 8));
      }
#pragma unroll
      for (int i = 0; i < 4; i++)
#pragma unroll
        for (int j = 0; j < 4; j++)
          acc[i][j] = __builtin_amdgcn_mfma_f32_16x16x32_bf16(af[i], bfr[j], acc[i][j], 0, 0, 0);
    }
    __syncthreads();
  }
#pragma unroll
  for (int i = 0; i < 4; i++) {
#pragma unroll
    for (int j = 0; j < 4; j++) {
      int col = n0 + wn + j * 16 + row_c;
#pragma unroll
      for (int r = 0; r < 4; r++) {
        int gm = m0 + wm + i * 16 + quad * 4 + r;
        if (gm < M) C[(size_t)gm * N + col] = f2bf(acc[i][j][r]);
      }
    }
  }
}

// ---------- bucketed CSR aggregation: one wave per 16 nodes ----------
__global__ __launch_bounds__(256) void k_agg1(const unsigned short* __restrict__ H,
                                              const int* __restrict__ bptr9,
                                              const int* __restrict__ col,
                                              const float* __restrict__ dis,
                                              const float* __restrict__ bias,
                                              unsigned short* __restrict__ OUT) {
  int wid = blockIdx.x * 4 + (threadIdx.x >> 6);
  int lane = threadIdx.x & 63;
  int n0 = wid * 16;
  if (n0 >= NN) return;
  float acc[16][4];
#pragma unroll
  for (int i = 0; i < 16; i++)
#pragma unroll
    for (int j = 0; j < 4; j++) acc[i][j] = 0.f;

  for (int b = 0; b < NBUCK; b++) {
#pragma unroll
    for (int i = 0; i < 16; i++) {
      int n = n0 + i;
      if (n >= NN) break;
      float dn = dis[n];
      if ((unsigned)n / BSZ == (unsigned)b) {  // self-loop in its home bucket
        ushort4 v = ((const ushort4*)(H + (size_t)n * D1))[lane];
        float w = dn * dn;
        acc[i][0] += w * bf2f(v.x);
        acc[i][1] += w * bf2f(v.y);
        acc[i][2] += w * bf2f(v.z);
        acc[i][3] += w * bf2f(v.w);
      }
      int e = bptr9[n * 9 + b], e1 = bptr9[n * 9 + b + 1];
      for (; e + 1 < e1; e += 2) {
        int sa = col[e], sb = col[e + 1];
        float wa = dis[sa] * dn, wb = dis[sb] * dn;
        ushort4 ua = ((const ushort4*)(H + (size_t)sa * D1))[lane];
        ushort4 ub = ((const ushort4*)(H + (size_t)sb * D1))[lane];
        acc[i][0] += wa * bf2f(ua.x) + wb * bf2f(ub.x);
        acc[i][1] += wa * bf2f(ua.y) + wb * bf2f(ub.y);
        acc[i][2] += wa * bf2f(ua.z) + wb * bf2f(ub.z);
        acc[i][3] += wa * bf2f(ua.w) + wb * bf2f(ub.w);
      }
      if (e < e1) {
        int sa = col[e];
        float wa = dis[sa] * dn;
        ushort4 ua = ((const ushort4*)(H + (size_t)sa * D1))[lane];
        acc[i][0] += wa * bf2f(ua.x);
        acc[i][1] += wa * bf2f(ua.y);
        acc[i][2] += wa * bf2f(ua.z);
        acc[i][3] += wa * bf2f(ua.w);
      }
    }
  }
  int c = lane * 4;
  float b0 = bias[c], b1 = bias[c + 1], b2 = bias[c + 2], b3 = bias[c + 3];
#pragma unroll
  for (int i = 0; i < 16; i++) {
    int n = n0 + i;
    if (n >= NN) break;
    ushort4 o;
    o.x = f2bf(acc[i][0] + b0);
    o.y = f2bf(acc[i][1] + b1);
    o.z = f2bf(acc[i][2] + b2);
    o.w = f2bf(acc[i][3] + b3);
    ((ushort4*)(OUT + (size_t)n * D1))[lane] = o;
  }
}

__global__ __launch_bounds__(256) void k_agg2(const unsigned short* __restrict__ H,
                                              const int* __restrict__ bptr9,
                                              const int* __restrict__ col,
                                              const float* __restrict__ dis,
                                              const float* __restrict__ bias,
                                              float* __restrict__ OUT) {
  int wid = blockIdx.x * 4 + (threadIdx.x >> 6);
  int lane = threadIdx.x & 63;
  int n0 = wid * 16;
  if (n0 >= NN) return;
  float acc[16][2];
#pragma unroll
  for (int i = 0; i < 16; i++) {
    acc[i][0] = 0.f;
    acc[i][1] = 0.f;
  }
  for (int b = 0; b < NBUCK; b++) {
#pragma unroll
    for (int i = 0; i < 16; i++) {
      int n = n0 + i;
      if (n >= NN) break;
      float dn = dis[n];
      if ((unsigned)n / BSZ == (unsigned)b) {
        ushort2 v = ((const ushort2*)(H + (size_t)n * D2))[lane];
        float w = dn * dn;
        acc[i][0] += w * bf2f(v.x);
        acc[i][1] += w * bf2f(v.y);
      }
      int e = bptr9[n * 9 + b], e1 = bptr9[n * 9 + b + 1];
      for (; e + 1 < e1; e += 2) {
        int sa = col[e], sb = col[e + 1];
        float wa = dis[sa] * dn, wb = dis[sb] * dn;
        ushort2 ua = ((const ushort2*)(H + (size_t)sa * D2))[lane];
        ushort2 ub = ((const ushort2*)(H + (size_t)sb * D2))[lane];
        acc[i][0] += wa * bf2f(ua.x) + wb * bf2f(ub.x);
        acc[i][1] += wa * bf2f(ua.y) + wb * bf2f(ub.y);
      }
      if (e < e1) {
        int sa = col[e];
        float wa = dis[sa] * dn;
        ushort2 ua = ((const ushort2*)(H + (size_t)sa * D2))[lane];
        acc[i][0] += wa * bf2f(ua.x);
        acc[i][1] += wa * bf2f(ua.y);
      }
    }
  }
  int c = lane * 2;
  float b0 = bias[c], b1 = bias[c + 1];
#pragma unroll
  for (int i = 0; i < 16; i++) {
    int n = n0 + i;
    if (n >= NN) break;
    ((float2*)(OUT + (size_t)n * D2))[lane] = make_float2(acc[i][0] + b0, acc[i][1] + b1);
  }
}

// ---------- BatchNorm ----------
__global__ void k_stats1(const unsigned short* __restrict__ X, float* __restrict__ stats) {
  int t = threadIdx.x;  // column 0..255
  int r0 = blockIdx.x * 64;
  int r1 = (r0 + 64 < NN) ? r0 + 64 : NN;
  float s = 0.f, q = 0.f;
  for (int r = r0; r < r1; r++) {
    float v = bf2f(X[(size_t)r * D1 + t]);
    s += v;
    q += v * v;
  }
  atomicAdd(&stats[t], s);
  atomicAdd(&stats[D1 + t], q);
}

__global__ void k_apply1(unsigned short* __restrict__ X, const float* __restrict__ stats,
                         const float* __restrict__ gamma, const float* __restrict__ beta) {
  int i = blockIdx.x * blockDim.x + threadIdx.x;
  int c = i & (D1 - 1);
  float mean = stats[c] * (1.0f / NN);
  float var = stats[D1 + c] * (1.0f / NN) - mean * mean;
  float sc = gamma[c] * rsqrtf(var + EPSV);
  float v = (bf2f(X[i]) - mean) * sc + beta[c];
  X[i] = f2bf(fmaxf(v, 0.0f));  // fused ReLU
}

__global__ void k_stats2(const float* __restrict__ X, float* __restrict__ stats) {
  int t = threadIdx.x;  // column 0..127
  int r0 = blockIdx.x * 128;
  int r1 = (r0 + 128 < NN) ? r0 + 128 : NN;
  float s = 0.f, q = 0.f;
  for (int r = r0; r < r1; r++) {
    float v = X[(size_t)r * D2 + t];
    s += v;
    q += v * v;
  }
  atomicAdd(&stats[t], s);
  atomicAdd(&stats[D2 + t], q);
}

__global__ void k_apply2(float* __restrict__ X, const float* __restrict__ stats,
                         const float* __restrict__ gamma, const float* __restrict__ beta) {
  int i = blockIdx.x * blockDim.x + threadIdx.x;
  int c = i & (D2 - 1);
  float mean = stats[c] * (1.0f / NN);
  float var = stats[D2 + c] * (1.0f / NN) - mean * mean;
  float sc = gamma[c] * rsqrtf(var + EPSV);
  X[i] = (X[i] - mean) * sc + beta[c];
}

extern "C" void kernel_launch(void* const* d_in, const int* in_sizes, int n_in,
                              void* d_out, int out_size, void* d_ws, size_t ws_size,
                              hipStream_t stream) {
  const float* x  = (const float*)d_in[0];
  const int* ei   = (const int*)d_in[1];  // [2, NE], int32
  const int* srcv = ei;
  const int* dstv = ei + NE;
  const float* W1  = (const float*)d_in[2];
  const float* b1  = (const float*)d_in[3];
  const float* g1  = (const float*)d_in[4];
  const float* be1 = (const float*)d_in[5];
  const float* W2  = (const float*)d_in[6];
  const float* b2  = (const float*)d_in[7];
  const float* g2  = (const float*)d_in[8];
  const float* be2 = (const float*)d_in[9];
  float* out = (float*)d_out;

  char* ws = (char*)d_ws;
  size_t off = 0;
  auto alloc = [&](size_t bytes) {
    size_t cur = off;
    off = (off + bytes + 255) & ~(size_t)255;
    return cur;
  };
  int* cnt       = (int*)(ws + alloc(NN * 4));
  int* row_ptr   = (int*)(ws + alloc((NN + 1) * 4));
  float* dis     = (float*)(ws + alloc(NN * 4));
  int* part      = (int*)(ws + alloc(256 * 4));
  float* stats   = (float*)(ws + alloc((D1 * 2 + D2 * 2) * 4));
  int* cnt2      = (int*)(ws + alloc((size_t)NN * NBUCK * 4));
  int* bptr9     = (int*)(ws + alloc((size_t)NN * 9 * 4));
  int* col       = (int*)(ws + alloc((size_t)NE * 4));
  unsigned short* H1  = (unsigned short*)(ws + alloc((size_t)NN * D1 * 2));
  unsigned short* A1  = (unsigned short*)(ws + alloc((size_t)NN * D1 * 2));
  unsigned short* H2  = (unsigned short*)(ws + alloc((size_t)NN * D2 * 2));
  unsigned short* W1t = (unsigned short*)(ws + alloc((size_t)DIN * D1 * 2));
  unsigned short* W2t = (unsigned short*)(ws + alloc((size_t)D1 * D2 * 2));
  float* stats2 = stats + D1 * 2;

  const int nb = (NN + 255) / 256;            // 196
  const int nbz = (NN * NBUCK + 255) / 256;   // covers cnt2 zeroing

  // bucketed CSR build
  k_zero<<<nbz, 256, 0, stream>>>(cnt, cnt2, stats);
  k_hist<<<NE / 256, 256, 0, stream>>>(srcv, dstv, cnt, cnt2);
  k_scan_partial<<<nb, 256, 0, stream>>>(cnt, part);
  k_scan_block<<<1, 256, 0, stream>>>(part, nb);
  k_scan_final<<<nb, 256, 0, stream>>>(cnt, part, row_ptr, dis);
  k_brow<<<nb, 256, 0, stream>>>(row_ptr, cnt2, bptr9);
  k_fill<<<NE / 256, 256, 0, stream>>>(srcv, dstv, cnt2, col);

  // weight transpose + bf16 convert
  k_prep_w<<<(DIN * D1 + D1 * D2) / 256, 256, 0, stream>>>(W1, W2, W1t, W2t);

  const int mb = (NN + 127) / 128;  // 391
  const int ab = (NN + 63) / 64;    // 782 blocks: wave = 16 nodes, 4 waves/block

  // conv1
  k_gemm_mfma<DIN, true><<<dim3(mb, D1 / 128), 256, 0, stream>>>(x, W1t, H1, NN, D1);
  k_agg1<<<ab, 256, 0, stream>>>(H1, bptr9, col, dis, b1, A1);
  k_stats1<<<(NN + 63) / 64, 256, 0, stream>>>(A1, stats);
  k_apply1<<<NN * D1 / 256, 256, 0, stream>>>(A1, stats, g1, be1);

  // conv2
  k_gemm_mfma<D1, false><<<dim3(mb, D2 / 128), 256, 0, stream>>>(A1, W2t, H2, NN, D2);
  k_agg2<<<ab, 256, 0, stream>>>(H2, bptr9, col, dis, b2, out);
  k_stats2<<<(NN + 127) / 128, 128, 0, stream>>>(out, stats2);
  k_apply2<<<NN * D2 / 256, 256, 0, stream>>>(out, stats2, g2, be2);
}

// Round 4
// 743.505 us; speedup vs baseline: 4.5031x; 4.5031x over previous
//
#include <hip/hip_runtime.h>
#include <hip/hip_bf16.h>

// GCN encoder: conv1(512->256) -> BN -> ReLU -> conv2(256->128) -> BN
// R4: R2's wave-per-node aggregation (4 fp32 acc in regs, no spill) + bucket-
// sorted adjacency (col sorted by 8 src-range buckets within each node's list).
// Co-resident waves walk buckets in the same order -> soft lockstep -> gather
// working set ~3.2 MB fits per-XCD L2. Edge loop unrolled x4 for MLP.
// R3 failed on register spill (acc[16][4] + break defeated unroll: VGPR=256,
// WRITE_SIZE=5.9GB scratch traffic) -- keep per-wave accumulator state at 4 floats.

#define NN 50000
#define NE 1600000
#define DIN 512
#define D1 256
#define D2 128
#define EPSV 1e-5f
#define NBUCK 8
#define BSZ 6250  // nodes per bucket

typedef __attribute__((ext_vector_type(8))) short bf16x8_t;
typedef __attribute__((ext_vector_type(4))) float f32x4_t;

__device__ __forceinline__ float bf2f(unsigned short u) {
  return __uint_as_float(((unsigned int)u) << 16);
}
__device__ __forceinline__ unsigned short f2bf(float f) {
  unsigned int u = __float_as_uint(f);
  u += 0x7fffu + ((u >> 16) & 1u);   // RNE
  return (unsigned short)(u >> 16);
}
__device__ __forceinline__ unsigned int pk2(float a, float b) {
  __hip_bfloat162 h = __float22bfloat162_rn(make_float2(a, b));
  union { __hip_bfloat162 h; unsigned int u; } c;
  c.h = h;
  return c.u;
}

// ---------- CSR build (bucketed) ----------
__global__ void k_zero(int* __restrict__ cnt, int* __restrict__ cnt2,
                       float* __restrict__ stats) {
  int i = blockIdx.x * blockDim.x + threadIdx.x;
  if (i < NN) cnt[i] = 0;
  if (i < NN * NBUCK) cnt2[i] = 0;
  if (i < (D1 * 2 + D2 * 2)) stats[i] = 0.0f;
}

__global__ void k_hist(const int* __restrict__ src, const int* __restrict__ dst,
                       int* __restrict__ cnt, int* __restrict__ cnt2) {
  int e = blockIdx.x * blockDim.x + threadIdx.x;
  if (e < NE) {
    int d = dst[e];
    int b = (unsigned)src[e] / BSZ;
    atomicAdd(&cnt[d], 1);
    atomicAdd(&cnt2[d * NBUCK + b], 1);
  }
}

__global__ void k_scan_partial(const int* __restrict__ cnt, int* __restrict__ part) {
  __shared__ int s[256];
  int t = threadIdx.x;
  int i = blockIdx.x * 256 + t;
  s[t] = (i < NN) ? cnt[i] : 0;
  __syncthreads();
  for (int off = 128; off > 0; off >>= 1) {
    if (t < off) s[t] += s[t + off];
    __syncthreads();
  }
  if (t == 0) part[blockIdx.x] = s[0];
}

__global__ void k_scan_block(int* __restrict__ part, int nb) {
  __shared__ int s[256];
  int t = threadIdx.x;
  int v = (t < nb) ? part[t] : 0;
  s[t] = v;
  __syncthreads();
  for (int off = 1; off < 256; off <<= 1) {
    int add = (t >= off) ? s[t - off] : 0;
    __syncthreads();
    s[t] += add;
    __syncthreads();
  }
  part[t] = s[t] - v;  // exclusive block offsets
}

__global__ void k_scan_final(const int* __restrict__ cnt, const int* __restrict__ boff,
                             int* __restrict__ row_ptr, float* __restrict__ dis) {
  __shared__ int s[256];
  int t = threadIdx.x;
  int i = blockIdx.x * 256 + t;
  int v = (i < NN) ? cnt[i] : 0;
  s[t] = v;
  __syncthreads();
  for (int off = 1; off < 256; off <<= 1) {
    int add = (t >= off) ? s[t - off] : 0;
    __syncthreads();
    s[t] += add;
    __syncthreads();
  }
  if (i < NN) {
    int excl = boff[blockIdx.x] + s[t] - v;
    row_ptr[i] = excl;
    dis[i] = rsqrtf((float)(v + 1));  // self-loop guarantees deg>=1
    if (i == NN - 1) row_ptr[NN] = excl + v;
  }
}

// turn cnt2 into per-(node,bucket) fill cursors (in place)
__global__ void k_brow(const int* __restrict__ row_ptr, int* __restrict__ cnt2) {
  int n = blockIdx.x * 256 + threadIdx.x;
  if (n < NN) {
    int base = row_ptr[n];
#pragma unroll
    for (int b = 0; b < NBUCK; b++) {
      int c = cnt2[n * NBUCK + b];
      cnt2[n * NBUCK + b] = base;
      base += c;
    }
  }
}

__global__ void k_fill(const int* __restrict__ src, const int* __restrict__ dst,
                       int* __restrict__ cnt2, int* __restrict__ col) {
  int e = blockIdx.x * blockDim.x + threadIdx.x;
  if (e < NE) {
    int s = src[e], d = dst[e];
    int b = (unsigned)s / BSZ;
    int pos = atomicAdd(&cnt2[d * NBUCK + b], 1);
    col[pos] = s;
  }
}

// ---------- weight prep: W [KxN] fp32 -> Wt [NxK] bf16 ----------
__global__ void k_prep_w(const float* __restrict__ W1, const float* __restrict__ W2,
                         unsigned short* __restrict__ W1t, unsigned short* __restrict__ W2t) {
  int i = blockIdx.x * 256 + threadIdx.x;
  if (i < DIN * D1) {  // W1t[n*DIN + k] = W1[k*D1 + n]
    int n = i / DIN, k = i - n * DIN;
    W1t[i] = f2bf(W1[(size_t)k * D1 + n]);
  } else {
    int j = i - DIN * D1;  // W2t[n*D1 + k] = W2[k*D2 + n]
    int n = j / D1, k = j - n * D1;
    W2t[j] = f2bf(W2[(size_t)k * D2 + n]);
  }
}

// ---------- MFMA GEMM: C[MxN] bf16 = A[MxK] @ Bt[NxK]^T, fp32 accum ----------
template <int K, bool A_IS_F32>
__global__ __launch_bounds__(256) void k_gemm_mfma(const void* __restrict__ Ap,
                                                   const unsigned short* __restrict__ Bt,
                                                   unsigned short* __restrict__ C,
                                                   int M, int N) {
  __shared__ unsigned short As[128 * 64];
  __shared__ unsigned short Bs[128 * 64];
  const int t = threadIdx.x;
  const int wave = t >> 6, lane = t & 63;
  const int m0 = blockIdx.x * 128, n0 = blockIdx.y * 128;
  const int wm = (wave >> 1) * 64, wn = (wave & 1) * 64;
  const int l8 = lane >> 3;
  const int lbs = (lane & 7) ^ l8;  // logical k-block for staging
  const int row_c = lane & 15, quad = lane >> 4;

  f32x4_t acc[4][4];
#pragma unroll
  for (int i = 0; i < 4; i++)
#pragma unroll
    for (int j = 0; j < 4; j++) acc[i][j] = (f32x4_t){0.f, 0.f, 0.f, 0.f};

  for (int k0 = 0; k0 < K; k0 += 64) {
#pragma unroll
    for (int j = 0; j < 4; j++) {
      int chunk = wave * 4 + j;
      int row = chunk * 8 + l8;
      const unsigned short* g = Bt + (size_t)(n0 + row) * K + k0 + lbs * 8;
      __builtin_amdgcn_global_load_lds(
          (const __attribute__((address_space(1))) unsigned int*)g,
          (__attribute__((address_space(3))) unsigned int*)(Bs + chunk * 512), 16, 0, 0);
    }
    if (A_IS_F32) {
      const float* A = (const float*)Ap;
#pragma unroll
      for (int i = 0; i < 4; i++) {
        int bid = i * 256 + t;
        int row = bid >> 3, pb = bid & 7;
        int lb = pb ^ (row & 7);
        int gm = m0 + row;
        if (gm >= M) gm = M - 1;
        const float4* s = (const float4*)(A + (size_t)gm * K + k0 + lb * 8);
        float4 v0 = s[0], v1 = s[1];
        uint4 o;
        o.x = pk2(v0.x, v0.y);
        o.y = pk2(v0.z, v0.w);
        o.z = pk2(v1.x, v1.y);
        o.w = pk2(v1.z, v1.w);
        *(uint4*)(As + row * 64 + pb * 8) = o;
      }
    } else {
      const unsigned short* A = (const unsigned short*)Ap;
#pragma unroll
      for (int j = 0; j < 4; j++) {
        int chunk = wave * 4 + j;
        int row = chunk * 8 + l8;
        int gm = m0 + row;
        if (gm >= M) gm = M - 1;
        const unsigned short* g = A + (size_t)gm * K + k0 + lbs * 8;
        __builtin_amdgcn_global_load_lds(
            (const __attribute__((address_space(1))) unsigned int*)g,
            (__attribute__((address_space(3))) unsigned int*)(As + chunk * 512), 16, 0, 0);
      }
    }
    __syncthreads();
#pragma unroll
    for (int ki = 0; ki < 2; ki++) {
      bf16x8_t af[4], bfr[4];
      int kb = ki * 4 + quad;
#pragma unroll
      for (int i = 0; i < 4; i++) {
        int ar = wm + i * 16 + row_c;
        af[i] = *(const bf16x8_t*)(As + ar * 64 + ((kb ^ (ar & 7)) * 8));
        int br = wn + i * 16 + row_c;
        bfr[i] = *(const bf16x8_t*)(Bs + br * 64 + ((kb ^ (br & 7)) * 8));
      }
#pragma unroll
      for (int i = 0; i < 4; i++)
#pragma unroll
        for (int j = 0; j < 4; j++)
          acc[i][j] = __builtin_amdgcn_mfma_f32_16x16x32_bf16(af[i], bfr[j], acc[i][j], 0, 0, 0);
    }
    __syncthreads();
  }
#pragma unroll
  for (int i = 0; i < 4; i++) {
#pragma unroll
    for (int j = 0; j < 4; j++) {
      int col = n0 + wn + j * 16 + row_c;
#pragma unroll
      for (int r = 0; r < 4; r++) {
        int gm = m0 + wm + i * 16 + quad * 4 + r;
        if (gm < M) C[(size_t)gm * N + col] = f2bf(acc[i][j][r]);
      }
    }
  }
}

// ---------- CSR aggregation: one wave per node (col is bucket-sorted) ----------
__global__ __launch_bounds__(256) void k_agg1(const unsigned short* __restrict__ H,
                                              const int* __restrict__ row_ptr,
                                              const int* __restrict__ col,
                                              const float* __restrict__ dis,
                                              const float* __restrict__ bias,
                                              unsigned short* __restrict__ OUT) {
  int n = blockIdx.x * 4 + (threadIdx.x >> 6);
  int lane = threadIdx.x & 63;
  if (n >= NN) return;
  float dn = dis[n];
  ushort4 v = ((const ushort4*)(H + (size_t)n * D1))[lane];
  float wsf = dn * dn;
  float a0 = wsf * bf2f(v.x), a1 = wsf * bf2f(v.y);
  float a2 = wsf * bf2f(v.z), a3 = wsf * bf2f(v.w);
  int e = row_ptr[n], e1 = row_ptr[n + 1];
  for (; e + 3 < e1; e += 4) {
    int s0 = col[e], s1 = col[e + 1], s2 = col[e + 2], s3 = col[e + 3];
    float w0 = dis[s0] * dn, w1 = dis[s1] * dn;
    float w2 = dis[s2] * dn, w3 = dis[s3] * dn;
    ushort4 u0 = ((const ushort4*)(H + (size_t)s0 * D1))[lane];
    ushort4 u1 = ((const ushort4*)(H + (size_t)s1 * D1))[lane];
    ushort4 u2 = ((const ushort4*)(H + (size_t)s2 * D1))[lane];
    ushort4 u3 = ((const ushort4*)(H + (size_t)s3 * D1))[lane];
    a0 += w0 * bf2f(u0.x) + w1 * bf2f(u1.x) + w2 * bf2f(u2.x) + w3 * bf2f(u3.x);
    a1 += w0 * bf2f(u0.y) + w1 * bf2f(u1.y) + w2 * bf2f(u2.y) + w3 * bf2f(u3.y);
    a2 += w0 * bf2f(u0.z) + w1 * bf2f(u1.z) + w2 * bf2f(u2.z) + w3 * bf2f(u3.z);
    a3 += w0 * bf2f(u0.w) + w1 * bf2f(u1.w) + w2 * bf2f(u2.w) + w3 * bf2f(u3.w);
  }
  for (; e < e1; e++) {
    int sa = col[e];
    float wa = dis[sa] * dn;
    ushort4 ua = ((const ushort4*)(H + (size_t)sa * D1))[lane];
    a0 += wa * bf2f(ua.x);
    a1 += wa * bf2f(ua.y);
    a2 += wa * bf2f(ua.z);
    a3 += wa * bf2f(ua.w);
  }
  int c = lane * 4;
  a0 += bias[c]; a1 += bias[c + 1]; a2 += bias[c + 2]; a3 += bias[c + 3];
  ushort4 o;
  o.x = f2bf(a0); o.y = f2bf(a1); o.z = f2bf(a2); o.w = f2bf(a3);
  ((ushort4*)(OUT + (size_t)n * D1))[lane] = o;
}

__global__ __launch_bounds__(256) void k_agg2(const unsigned short* __restrict__ H,
                                              const int* __restrict__ row_ptr,
                                              const int* __restrict__ col,
                                              const float* __restrict__ dis,
                                              const float* __restrict__ bias,
                                              float* __restrict__ OUT) {
  int n = blockIdx.x * 4 + (threadIdx.x >> 6);
  int lane = threadIdx.x & 63;
  if (n >= NN) return;
  float dn = dis[n];
  ushort2 v = ((const ushort2*)(H + (size_t)n * D2))[lane];
  float wsf = dn * dn;
  float a0 = wsf * bf2f(v.x), a1 = wsf * bf2f(v.y);
  int e = row_ptr[n], e1 = row_ptr[n + 1];
  for (; e + 3 < e1; e += 4) {
    int s0 = col[e], s1 = col[e + 1], s2 = col[e + 2], s3 = col[e + 3];
    float w0 = dis[s0] * dn, w1 = dis[s1] * dn;
    float w2 = dis[s2] * dn, w3 = dis[s3] * dn;
    ushort2 u0 = ((const ushort2*)(H + (size_t)s0 * D2))[lane];
    ushort2 u1 = ((const ushort2*)(H + (size_t)s1 * D2))[lane];
    ushort2 u2 = ((const ushort2*)(H + (size_t)s2 * D2))[lane];
    ushort2 u3 = ((const ushort2*)(H + (size_t)s3 * D2))[lane];
    a0 += w0 * bf2f(u0.x) + w1 * bf2f(u1.x) + w2 * bf2f(u2.x) + w3 * bf2f(u3.x);
    a1 += w0 * bf2f(u0.y) + w1 * bf2f(u1.y) + w2 * bf2f(u2.y) + w3 * bf2f(u3.y);
  }
  for (; e < e1; e++) {
    int sa = col[e];
    float wa = dis[sa] * dn;
    ushort2 ua = ((const ushort2*)(H + (size_t)sa * D2))[lane];
    a0 += wa * bf2f(ua.x);
    a1 += wa * bf2f(ua.y);
  }
  int c = lane * 2;
  a0 += bias[c]; a1 += bias[c + 1];
  ((float2*)(OUT + (size_t)n * D2))[lane] = make_float2(a0, a1);
}

// ---------- BatchNorm ----------
__global__ void k_stats1(const unsigned short* __restrict__ X, float* __restrict__ stats) {
  int t = threadIdx.x;  // column 0..255
  int r0 = blockIdx.x * 64;
  int r1 = (r0 + 64 < NN) ? r0 + 64 : NN;
  float s = 0.f, q = 0.f;
  for (int r = r0; r < r1; r++) {
    float v = bf2f(X[(size_t)r * D1 + t]);
    s += v;
    q += v * v;
  }
  atomicAdd(&stats[t], s);
  atomicAdd(&stats[D1 + t], q);
}

__global__ void k_apply1(unsigned short* __restrict__ X, const float* __restrict__ stats,
                         const float* __restrict__ gamma, const float* __restrict__ beta) {
  int i = blockIdx.x * blockDim.x + threadIdx.x;
  int c = i & (D1 - 1);
  float mean = stats[c] * (1.0f / NN);
  float var = stats[D1 + c] * (1.0f / NN) - mean * mean;
  float sc = gamma[c] * rsqrtf(var + EPSV);
  float v = (bf2f(X[i]) - mean) * sc + beta[c];
  X[i] = f2bf(fmaxf(v, 0.0f));  // fused ReLU
}

__global__ void k_stats2(const float* __restrict__ X, float* __restrict__ stats) {
  int t = threadIdx.x;  // column 0..127
  int r0 = blockIdx.x * 128;
  int r1 = (r0 + 128 < NN) ? r0 + 128 : NN;
  float s = 0.f, q = 0.f;
  for (int r = r0; r < r1; r++) {
    float v = X[(size_t)r * D2 + t];
    s += v;
    q += v * v;
  }
  atomicAdd(&stats[t], s);
  atomicAdd(&stats[D2 + t], q);
}

__global__ void k_apply2(float* __restrict__ X, const float* __restrict__ stats,
                         const float* __restrict__ gamma, const float* __restrict__ beta) {
  int i = blockIdx.x * blockDim.x + threadIdx.x;
  int c = i & (D2 - 1);
  float mean = stats[c] * (1.0f / NN);
  float var = stats[D2 + c] * (1.0f / NN) - mean * mean;
  float sc = gamma[c] * rsqrtf(var + EPSV);
  X[i] = (X[i] - mean) * sc + beta[c];
}

extern "C" void kernel_launch(void* const* d_in, const int* in_sizes, int n_in,
                              void* d_out, int out_size, void* d_ws, size_t ws_size,
                              hipStream_t stream) {
  const float* x  = (const float*)d_in[0];
  const int* ei   = (const int*)d_in[1];  // [2, NE], int32
  const int* srcv = ei;
  const int* dstv = ei + NE;
  const float* W1  = (const float*)d_in[2];
  const float* b1  = (const float*)d_in[3];
  const float* g1  = (const float*)d_in[4];
  const float* be1 = (const float*)d_in[5];
  const float* W2  = (const float*)d_in[6];
  const float* b2  = (const float*)d_in[7];
  const float* g2  = (const float*)d_in[8];
  const float* be2 = (const float*)d_in[9];
  float* out = (float*)d_out;

  char* ws = (char*)d_ws;
  size_t off = 0;
  auto alloc = [&](size_t bytes) {
    size_t cur = off;
    off = (off + bytes + 255) & ~(size_t)255;
    return cur;
  };
  int* cnt       = (int*)(ws + alloc(NN * 4));
  int* row_ptr   = (int*)(ws + alloc((NN + 1) * 4));
  float* dis     = (float*)(ws + alloc(NN * 4));
  int* part      = (int*)(ws + alloc(256 * 4));
  float* stats   = (float*)(ws + alloc((D1 * 2 + D2 * 2) * 4));
  int* cnt2      = (int*)(ws + alloc((size_t)NN * NBUCK * 4));
  int* col       = (int*)(ws + alloc((size_t)NE * 4));
  unsigned short* H1  = (unsigned short*)(ws + alloc((size_t)NN * D1 * 2));
  unsigned short* A1  = (unsigned short*)(ws + alloc((size_t)NN * D1 * 2));
  unsigned short* H2  = (unsigned short*)(ws + alloc((size_t)NN * D2 * 2));
  unsigned short* W1t = (unsigned short*)(ws + alloc((size_t)DIN * D1 * 2));
  unsigned short* W2t = (unsigned short*)(ws + alloc((size_t)D1 * D2 * 2));
  float* stats2 = stats + D1 * 2;

  const int nb = (NN + 255) / 256;            // 196
  const int nbz = (NN * NBUCK + 255) / 256;   // covers cnt2 zeroing

  // bucketed CSR build (col ends up bucket-sorted within each node's list)
  k_zero<<<nbz, 256, 0, stream>>>(cnt, cnt2, stats);
  k_hist<<<NE / 256, 256, 0, stream>>>(srcv, dstv, cnt, cnt2);
  k_scan_partial<<<nb, 256, 0, stream>>>(cnt, part);
  k_scan_block<<<1, 256, 0, stream>>>(part, nb);
  k_scan_final<<<nb, 256, 0, stream>>>(cnt, part, row_ptr, dis);
  k_brow<<<nb, 256, 0, stream>>>(row_ptr, cnt2);
  k_fill<<<NE / 256, 256, 0, stream>>>(srcv, dstv, cnt2, col);

  // weight transpose + bf16 convert
  k_prep_w<<<(DIN * D1 + D1 * D2) / 256, 256, 0, stream>>>(W1, W2, W1t, W2t);

  const int mb = (NN + 127) / 128;  // 391

  // conv1
  k_gemm_mfma<DIN, true><<<dim3(mb, D1 / 128), 256, 0, stream>>>(x, W1t, H1, NN, D1);
  k_agg1<<<(NN + 3) / 4, 256, 0, stream>>>(H1, row_ptr, col, dis, b1, A1);
  k_stats1<<<(NN + 63) / 64, 256, 0, stream>>>(A1, stats);
  k_apply1<<<NN * D1 / 256, 256, 0, stream>>>(A1, stats, g1, be1);

  // conv2
  k_gemm_mfma<D1, false><<<dim3(mb, D2 / 128), 256, 0, stream>>>(A1, W2t, H2, NN, D2);
  k_agg2<<<(NN + 3) / 4, 256, 0, stream>>>(H2, row_ptr, col, dis, b2, out);
  k_stats2<<<(NN + 127) / 128, 128, 0, stream>>>(out, stats2);
  k_apply2<<<NN * D2 / 256, 256, 0, stream>>>(out, stats2, g2, be2);
}

// Round 5
// 651.997 us; speedup vs baseline: 5.1351x; 1.1404x over previous
//
#include <hip/hip_runtime.h>
#include <hip/hip_bf16.h>

// GCN encoder: conv1(512->256) -> BN -> ReLU -> conv2(256->128) -> BN
// R5: (1) k_hist does ONE atomic/edge into cnt2[node*8+bucket]; degree/row_ptr/
// bucket-cursors all derived by scanning cnt2 (k_brow merged into scan_final).
// (2) GEMM1 uses a 128Mx256N tile (512 thr, 8 waves, 48KB LDS) so x (102MB fp32)
// is read once, not twice. (3) BN1+ReLU fused into GEMM2's A-staging via
// per-column scale/shift (k_apply1 eliminated).
// R3 lesson: keep per-wave accumulator state tiny (spill = scratch traffic).

#define NN 50000
#define NE 1600000
#define DIN 512
#define D1 256
#define D2 128
#define EPSV 1e-5f
#define NBUCK 8
#define BSZ 6250  // nodes per bucket

typedef __attribute__((ext_vector_type(8))) short bf16x8_t;
typedef __attribute__((ext_vector_type(4))) float f32x4_t;

__device__ __forceinline__ float bf2f(unsigned short u) {
  return __uint_as_float(((unsigned int)u) << 16);
}
__device__ __forceinline__ unsigned short f2bf(float f) {
  unsigned int u = __float_as_uint(f);
  u += 0x7fffu + ((u >> 16) & 1u);   // RNE
  return (unsigned short)(u >> 16);
}
__device__ __forceinline__ unsigned int pk2(float a, float b) {
  __hip_bfloat162 h = __float22bfloat162_rn(make_float2(a, b));
  union { __hip_bfloat162 h; unsigned int u; } c;
  c.h = h;
  return c.u;
}

// ---------- CSR build (bucketed, single-atomic histogram) ----------
__global__ void k_zero(int* __restrict__ cnt2, float* __restrict__ stats) {
  int i = blockIdx.x * blockDim.x + threadIdx.x;
  if (i < NN * NBUCK) cnt2[i] = 0;
  if (i < (D1 * 2 + D2 * 2)) stats[i] = 0.0f;
}

__global__ void k_hist(const int* __restrict__ src, const int* __restrict__ dst,
                       int* __restrict__ cnt2) {
  int e = blockIdx.x * blockDim.x + threadIdx.x;
  if (e < NE) {
    int d = dst[e];
    int b = (unsigned)src[e] / BSZ;
    atomicAdd(&cnt2[d * NBUCK + b], 1);
  }
}

// per-node degree = sum of its 8 bucket counts
__global__ void k_scan_partial(const int* __restrict__ cnt2, int* __restrict__ part) {
  __shared__ int s[256];
  int t = threadIdx.x;
  int n = blockIdx.x * 256 + t;
  int v = 0;
  if (n < NN) {
    int4 a = ((const int4*)cnt2)[n * 2];
    int4 b = ((const int4*)cnt2)[n * 2 + 1];
    v = a.x + a.y + a.z + a.w + b.x + b.y + b.z + b.w;
  }
  s[t] = v;
  __syncthreads();
  for (int off = 128; off > 0; off >>= 1) {
    if (t < off) s[t] += s[t + off];
    __syncthreads();
  }
  if (t == 0) part[blockIdx.x] = s[0];
}

__global__ void k_scan_block(int* __restrict__ part, int nb) {
  __shared__ int s[256];
  int t = threadIdx.x;
  int v = (t < nb) ? part[t] : 0;
  s[t] = v;
  __syncthreads();
  for (int off = 1; off < 256; off <<= 1) {
    int add = (t >= off) ? s[t - off] : 0;
    __syncthreads();
    s[t] += add;
    __syncthreads();
  }
  part[t] = s[t] - v;  // exclusive block offsets
}

// row_ptr, dis, and in-place conversion of cnt2 counts -> fill cursors
__global__ void k_scan_final(int* __restrict__ cnt2, const int* __restrict__ boff,
                             int* __restrict__ row_ptr, float* __restrict__ dis) {
  __shared__ int s[256];
  int t = threadIdx.x;
  int n = blockIdx.x * 256 + t;
  int c[NBUCK];
  int v = 0;
  if (n < NN) {
    int4 a = ((const int4*)cnt2)[n * 2];
    int4 b = ((const int4*)cnt2)[n * 2 + 1];
    c[0] = a.x; c[1] = a.y; c[2] = a.z; c[3] = a.w;
    c[4] = b.x; c[5] = b.y; c[6] = b.z; c[7] = b.w;
#pragma unroll
    for (int i = 0; i < NBUCK; i++) v += c[i];
  }
  s[t] = v;
  __syncthreads();
  for (int off = 1; off < 256; off <<= 1) {
    int add = (t >= off) ? s[t - off] : 0;
    __syncthreads();
    s[t] += add;
    __syncthreads();
  }
  if (n < NN) {
    int base = boff[blockIdx.x] + s[t] - v;  // exclusive
    row_ptr[n] = base;
    dis[n] = rsqrtf((float)(v + 1));  // self-loop guarantees deg>=1
    int cur = base;
    int4 o0, o1;
    o0.x = cur; cur += c[0];
    o0.y = cur; cur += c[1];
    o0.z = cur; cur += c[2];
    o0.w = cur; cur += c[3];
    o1.x = cur; cur += c[4];
    o1.y = cur; cur += c[5];
    o1.z = cur; cur += c[6];
    o1.w = cur; cur += c[7];
    ((int4*)cnt2)[n * 2] = o0;
    ((int4*)cnt2)[n * 2 + 1] = o1;
    if (n == NN - 1) row_ptr[NN] = base + v;
  }
}

__global__ void k_fill(const int* __restrict__ src, const int* __restrict__ dst,
                       int* __restrict__ cnt2, int* __restrict__ col) {
  int e = blockIdx.x * blockDim.x + threadIdx.x;
  if (e < NE) {
    int s = src[e], d = dst[e];
    int b = (unsigned)s / BSZ;
    int pos = atomicAdd(&cnt2[d * NBUCK + b], 1);
    col[pos] = s;
  }
}

// ---------- weight prep: W [KxN] fp32 -> Wt [NxK] bf16 ----------
__global__ void k_prep_w(const float* __restrict__ W1, const float* __restrict__ W2,
                         unsigned short* __restrict__ W1t, unsigned short* __restrict__ W2t) {
  int i = blockIdx.x * 256 + threadIdx.x;
  if (i < DIN * D1) {  // W1t[n*DIN + k] = W1[k*D1 + n]
    int n = i / DIN, k = i - n * DIN;
    W1t[i] = f2bf(W1[(size_t)k * D1 + n]);
  } else {
    int j = i - DIN * D1;  // W2t[n*D1 + k] = W2[k*D2 + n]
    int n = j / D1, k = j - n * D1;
    W2t[j] = f2bf(W2[(size_t)k * D2 + n]);
  }
}

// ---------- GEMM1: H1[M x 256] = x[M x 512] @ W1t[256 x 512]^T ----------
// 512 threads (8 waves), 128M x 256N tile, BK=64. x read ONCE (one y-block).
__global__ __launch_bounds__(512) void k_gemm1(const float* __restrict__ A,
                                               const unsigned short* __restrict__ Bt,
                                               unsigned short* __restrict__ C, int M) {
  __shared__ unsigned short As[128 * 64];
  __shared__ unsigned short Bs[256 * 64];
  const int t = threadIdx.x;
  const int wave = t >> 6, lane = t & 63;
  const int m0 = blockIdx.x * 128;
  const int wm = (wave & 1) * 64, wn = (wave >> 1) * 64;  // 2x4 wave grid
  const int l8 = lane >> 3;
  const int lbs = (lane & 7) ^ l8;
  const int row_c = lane & 15, quad = lane >> 4;

  f32x4_t acc[4][4];
#pragma unroll
  for (int i = 0; i < 4; i++)
#pragma unroll
    for (int j = 0; j < 4; j++) acc[i][j] = (f32x4_t){0.f, 0.f, 0.f, 0.f};

  for (int k0 = 0; k0 < DIN; k0 += 64) {
    // B: 256 rows -> 32 chunks of 8 rows, 8 waves x 4
#pragma unroll
    for (int j = 0; j < 4; j++) {
      int chunk = wave * 4 + j;
      int row = chunk * 8 + l8;
      const unsigned short* g = Bt + (size_t)row * DIN + k0 + lbs * 8;
      __builtin_amdgcn_global_load_lds(
          (const __attribute__((address_space(1))) unsigned int*)g,
          (__attribute__((address_space(3))) unsigned int*)(Bs + chunk * 512), 16, 0, 0);
    }
    // A: fp32 -> bf16, 128 rows x 8 chunks = 1024 chunk-of-8, 2 per thread
#pragma unroll
    for (int i = 0; i < 2; i++) {
      int bid = i * 512 + t;
      int row = bid >> 3, pb = bid & 7;
      int lb = pb ^ (row & 7);
      int gm = m0 + row;
      if (gm >= M) gm = M - 1;
      const float4* s = (const float4*)(A + (size_t)gm * DIN + k0 + lb * 8);
      float4 v0 = s[0], v1 = s[1];
      uint4 o;
      o.x = pk2(v0.x, v0.y);
      o.y = pk2(v0.z, v0.w);
      o.z = pk2(v1.x, v1.y);
      o.w = pk2(v1.z, v1.w);
      *(uint4*)(As + row * 64 + pb * 8) = o;
    }
    __syncthreads();
#pragma unroll
    for (int ki = 0; ki < 2; ki++) {
      bf16x8_t af[4], bfr[4];
      int kb = ki * 4 + quad;
#pragma unroll
      for (int i = 0; i < 4; i++) {
        int ar = wm + i * 16 + row_c;
        af[i] = *(const bf16x8_t*)(As + ar * 64 + ((kb ^ (ar & 7)) * 8));
        int br = wn + i * 16 + row_c;
        bfr[i] = *(const bf16x8_t*)(Bs + br * 64 + ((kb ^ (br & 7)) * 8));
      }
#pragma unroll
      for (int i = 0; i < 4; i++)
#pragma unroll
        for (int j = 0; j < 4; j++)
          acc[i][j] = __builtin_amdgcn_mfma_f32_16x16x32_bf16(af[i], bfr[j], acc[i][j], 0, 0, 0);
    }
    __syncthreads();
  }
#pragma unroll
  for (int i = 0; i < 4; i++) {
#pragma unroll
    for (int j = 0; j < 4; j++) {
      int colv = wn + j * 16 + row_c;
#pragma unroll
      for (int r = 0; r < 4; r++) {
        int gm = m0 + wm + i * 16 + quad * 4 + r;
        if (gm < M) C[(size_t)gm * D1 + colv] = f2bf(acc[i][j][r]);
      }
    }
  }
}

// per-column BN1 scale/shift from stats
__global__ void k_finalize1(const float* __restrict__ stats, const float* __restrict__ gamma,
                            const float* __restrict__ beta, float* __restrict__ sc1,
                            float* __restrict__ sh1) {
  int c = threadIdx.x;  // 256
  float mean = stats[c] * (1.0f / NN);
  float var = stats[D1 + c] * (1.0f / NN) - mean * mean;
  float sc = gamma[c] * rsqrtf(var + EPSV);
  sc1[c] = sc;
  sh1[c] = beta[c] - mean * sc;
}

// ---------- GEMM2: H2[M x 128] = relu(BN(A1))[M x 256] @ W2t[128 x 256]^T ----------
// BN1+ReLU fused into A-staging (A1 holds RAW conv1 output).
__global__ __launch_bounds__(256) void k_gemm2(const unsigned short* __restrict__ A,
                                               const float* __restrict__ sc1,
                                               const float* __restrict__ sh1,
                                               const unsigned short* __restrict__ Bt,
                                               unsigned short* __restrict__ C, int M) {
  __shared__ unsigned short As[128 * 64];
  __shared__ unsigned short Bs[128 * 64];
  const int t = threadIdx.x;
  const int wave = t >> 6, lane = t & 63;
  const int m0 = blockIdx.x * 128;
  const int wm = (wave >> 1) * 64, wn = (wave & 1) * 64;
  const int l8 = lane >> 3;
  const int lbs = (lane & 7) ^ l8;
  const int row_c = lane & 15, quad = lane >> 4;

  f32x4_t acc[4][4];
#pragma unroll
  for (int i = 0; i < 4; i++)
#pragma unroll
    for (int j = 0; j < 4; j++) acc[i][j] = (f32x4_t){0.f, 0.f, 0.f, 0.f};

  for (int k0 = 0; k0 < D1; k0 += 64) {
#pragma unroll
    for (int j = 0; j < 2; j++) {  // B: 128 rows -> 16 chunks, 4 waves x 4
      int chunk = wave * 2 + j + ((j >> 1) * 0);
      chunk = wave * 4 + j;  // keep 4-chunk stride layout; j<2 handled below
      (void)chunk;
    }
    // B: 128 rows -> 16 chunks of 8 rows; 4 waves -> 4 chunks each
#pragma unroll
    for (int j = 0; j < 4; j++) {
      int chunk = wave * 4 + j;
      int row = chunk * 8 + l8;
      const unsigned short* g = Bt + (size_t)row * D1 + k0 + lbs * 8;
      __builtin_amdgcn_global_load_lds(
          (const __attribute__((address_space(1))) unsigned int*)g,
          (__attribute__((address_space(3))) unsigned int*)(Bs + chunk * 512), 16, 0, 0);
    }
    // A: bf16 raw -> BN+ReLU -> bf16 ; 1024 chunk-of-8, 4 per thread
#pragma unroll
    for (int i = 0; i < 4; i++) {
      int bid = i * 256 + t;
      int row = bid >> 3, pb = bid & 7;
      int lb = pb ^ (row & 7);
      int gm = m0 + row;
      if (gm >= M) gm = M - 1;
      int colb = k0 + lb * 8;
      uint4 raw = *(const uint4*)(A + (size_t)gm * D1 + colb);
      float4 scA = *(const float4*)(sc1 + colb);
      float4 scB = *(const float4*)(sc1 + colb + 4);
      float4 shA = *(const float4*)(sh1 + colb);
      float4 shB = *(const float4*)(sh1 + colb + 4);
      float f0 = fmaxf(fmaf(bf2f((unsigned short)(raw.x & 0xffff)), scA.x, shA.x), 0.f);
      float f1 = fmaxf(fmaf(bf2f((unsigned short)(raw.x >> 16)),    scA.y, shA.y), 0.f);
      float f2 = fmaxf(fmaf(bf2f((unsigned short)(raw.y & 0xffff)), scA.z, shA.z), 0.f);
      float f3 = fmaxf(fmaf(bf2f((unsigned short)(raw.y >> 16)),    scA.w, shA.w), 0.f);
      float f4 = fmaxf(fmaf(bf2f((unsigned short)(raw.z & 0xffff)), scB.x, shB.x), 0.f);
      float f5 = fmaxf(fmaf(bf2f((unsigned short)(raw.z >> 16)),    scB.y, shB.y), 0.f);
      float f6 = fmaxf(fmaf(bf2f((unsigned short)(raw.w & 0xffff)), scB.z, shB.z), 0.f);
      float f7 = fmaxf(fmaf(bf2f((unsigned short)(raw.w >> 16)),    scB.w, shB.w), 0.f);
      uint4 o;
      o.x = pk2(f0, f1);
      o.y = pk2(f2, f3);
      o.z = pk2(f4, f5);
      o.w = pk2(f6, f7);
      *(uint4*)(As + row * 64 + pb * 8) = o;
    }
    __syncthreads();
#pragma unroll
    for (int ki = 0; ki < 2; ki++) {
      bf16x8_t af[4], bfr[4];
      int kb = ki * 4 + quad;
#pragma unroll
      for (int i = 0; i < 4; i++) {
        int ar = wm + i * 16 + row_c;
        af[i] = *(const bf16x8_t*)(As + ar * 64 + ((kb ^ (ar & 7)) * 8));
        int br = wn + i * 16 + row_c;
        bfr[i] = *(const bf16x8_t*)(Bs + br * 64 + ((kb ^ (br & 7)) * 8));
      }
#pragma unroll
      for (int i = 0; i < 4; i++)
#pragma unroll
        for (int j = 0; j < 4; j++)
          acc[i][j] = __builtin_amdgcn_mfma_f32_16x16x32_bf16(af[i], bfr[j], acc[i][j], 0, 0, 0);
    }
    __syncthreads();
  }
#pragma unroll
  for (int i = 0; i < 4; i++) {
#pragma unroll
    for (int j = 0; j < 4; j++) {
      int colv = wn + j * 16 + row_c;
      if (colv < D2) {
#pragma unroll
        for (int r = 0; r < 4; r++) {
          int gm = m0 + wm + i * 16 + quad * 4 + r;
          if (gm < M) C[(size_t)gm * D2 + colv] = f2bf(acc[i][j][r]);
        }
      }
    }
  }
}

// ---------- CSR aggregation: one wave per node (col is bucket-sorted) ----------
__global__ __launch_bounds__(256) void k_agg1(const unsigned short* __restrict__ H,
                                              const int* __restrict__ row_ptr,
                                              const int* __restrict__ col,
                                              const float* __restrict__ dis,
                                              const float* __restrict__ bias,
                                              unsigned short* __restrict__ OUT) {
  int n = blockIdx.x * 4 + (threadIdx.x >> 6);
  int lane = threadIdx.x & 63;
  if (n >= NN) return;
  float dn = dis[n];
  ushort4 v = ((const ushort4*)(H + (size_t)n * D1))[lane];
  float wsf = dn * dn;
  float a0 = wsf * bf2f(v.x), a1 = wsf * bf2f(v.y);
  float a2 = wsf * bf2f(v.z), a3 = wsf * bf2f(v.w);
  int e = row_ptr[n], e1 = row_ptr[n + 1];
  for (; e + 3 < e1; e += 4) {
    int s0 = col[e], s1 = col[e + 1], s2 = col[e + 2], s3 = col[e + 3];
    float w0 = dis[s0] * dn, w1 = dis[s1] * dn;
    float w2 = dis[s2] * dn, w3 = dis[s3] * dn;
    ushort4 u0 = ((const ushort4*)(H + (size_t)s0 * D1))[lane];
    ushort4 u1 = ((const ushort4*)(H + (size_t)s1 * D1))[lane];
    ushort4 u2 = ((const ushort4*)(H + (size_t)s2 * D1))[lane];
    ushort4 u3 = ((const ushort4*)(H + (size_t)s3 * D1))[lane];
    a0 += w0 * bf2f(u0.x) + w1 * bf2f(u1.x) + w2 * bf2f(u2.x) + w3 * bf2f(u3.x);
    a1 += w0 * bf2f(u0.y) + w1 * bf2f(u1.y) + w2 * bf2f(u2.y) + w3 * bf2f(u3.y);
    a2 += w0 * bf2f(u0.z) + w1 * bf2f(u1.z) + w2 * bf2f(u2.z) + w3 * bf2f(u3.z);
    a3 += w0 * bf2f(u0.w) + w1 * bf2f(u1.w) + w2 * bf2f(u2.w) + w3 * bf2f(u3.w);
  }
  for (; e < e1; e++) {
    int sa = col[e];
    float wa = dis[sa] * dn;
    ushort4 ua = ((const ushort4*)(H + (size_t)sa * D1))[lane];
    a0 += wa * bf2f(ua.x);
    a1 += wa * bf2f(ua.y);
    a2 += wa * bf2f(ua.z);
    a3 += wa * bf2f(ua.w);
  }
  int c = lane * 4;
  a0 += bias[c]; a1 += bias[c + 1]; a2 += bias[c + 2]; a3 += bias[c + 3];
  ushort4 o;
  o.x = f2bf(a0); o.y = f2bf(a1); o.z = f2bf(a2); o.w = f2bf(a3);
  ((ushort4*)(OUT + (size_t)n * D1))[lane] = o;
}

__global__ __launch_bounds__(256) void k_agg2(const unsigned short* __restrict__ H,
                                              const int* __restrict__ row_ptr,
                                              const int* __restrict__ col,
                                              const float* __restrict__ dis,
                                              const float* __restrict__ bias,
                                              float* __restrict__ OUT) {
  int n = blockIdx.x * 4 + (threadIdx.x >> 6);
  int lane = threadIdx.x & 63;
  if (n >= NN) return;
  float dn = dis[n];
  ushort2 v = ((const ushort2*)(H + (size_t)n * D2))[lane];
  float wsf = dn * dn;
  float a0 = wsf * bf2f(v.x), a1 = wsf * bf2f(v.y);
  int e = row_ptr[n], e1 = row_ptr[n + 1];
  for (; e + 3 < e1; e += 4) {
    int s0 = col[e], s1 = col[e + 1], s2 = col[e + 2], s3 = col[e + 3];
    float w0 = dis[s0] * dn, w1 = dis[s1] * dn;
    float w2 = dis[s2] * dn, w3 = dis[s3] * dn;
    ushort2 u0 = ((const ushort2*)(H + (size_t)s0 * D2))[lane];
    ushort2 u1 = ((const ushort2*)(H + (size_t)s1 * D2))[lane];
    ushort2 u2 = ((const ushort2*)(H + (size_t)s2 * D2))[lane];
    ushort2 u3 = ((const ushort2*)(H + (size_t)s3 * D2))[lane];
    a0 += w0 * bf2f(u0.x) + w1 * bf2f(u1.x) + w2 * bf2f(u2.x) + w3 * bf2f(u3.x);
    a1 += w0 * bf2f(u0.y) + w1 * bf2f(u1.y) + w2 * bf2f(u2.y) + w3 * bf2f(u3.y);
  }
  for (; e < e1; e++) {
    int sa = col[e];
    float wa = dis[sa] * dn;
    ushort2 ua = ((const ushort2*)(H + (size_t)sa * D2))[lane];
    a0 += wa * bf2f(ua.x);
    a1 += wa * bf2f(ua.y);
  }
  int c = lane * 2;
  a0 += bias[c]; a1 += bias[c + 1];
  ((float2*)(OUT + (size_t)n * D2))[lane] = make_float2(a0, a1);
}

// ---------- BatchNorm stats ----------
__global__ void k_stats1(const unsigned short* __restrict__ X, float* __restrict__ stats) {
  int t = threadIdx.x;  // column 0..255
  int r0 = blockIdx.x * 64;
  int r1 = (r0 + 64 < NN) ? r0 + 64 : NN;
  float s = 0.f, q = 0.f;
  for (int r = r0; r < r1; r++) {
    float v = bf2f(X[(size_t)r * D1 + t]);
    s += v;
    q += v * v;
  }
  atomicAdd(&stats[t], s);
  atomicAdd(&stats[D1 + t], q);
}

__global__ void k_stats2(const float* __restrict__ X, float* __restrict__ stats) {
  int t = threadIdx.x;  // column 0..127
  int r0 = blockIdx.x * 128;
  int r1 = (r0 + 128 < NN) ? r0 + 128 : NN;
  float s = 0.f, q = 0.f;
  for (int r = r0; r < r1; r++) {
    float v = X[(size_t)r * D2 + t];
    s += v;
    q += v * v;
  }
  atomicAdd(&stats[t], s);
  atomicAdd(&stats[D2 + t], q);
}

__global__ void k_apply2(float* __restrict__ X, const float* __restrict__ stats,
                         const float* __restrict__ gamma, const float* __restrict__ beta) {
  int i = blockIdx.x * blockDim.x + threadIdx.x;
  int c = i & (D2 - 1);
  float mean = stats[c] * (1.0f / NN);
  float var = stats[D2 + c] * (1.0f / NN) - mean * mean;
  float sc = gamma[c] * rsqrtf(var + EPSV);
  X[i] = (X[i] - mean) * sc + beta[c];
}

extern "C" void kernel_launch(void* const* d_in, const int* in_sizes, int n_in,
                              void* d_out, int out_size, void* d_ws, size_t ws_size,
                              hipStream_t stream) {
  const float* x  = (const float*)d_in[0];
  const int* ei   = (const int*)d_in[1];  // [2, NE], int32
  const int* srcv = ei;
  const int* dstv = ei + NE;
  const float* W1  = (const float*)d_in[2];
  const float* b1  = (const float*)d_in[3];
  const float* g1  = (const float*)d_in[4];
  const float* be1 = (const float*)d_in[5];
  const float* W2  = (const float*)d_in[6];
  const float* b2  = (const float*)d_in[7];
  const float* g2  = (const float*)d_in[8];
  const float* be2 = (const float*)d_in[9];
  float* out = (float*)d_out;

  char* ws = (char*)d_ws;
  size_t off = 0;
  auto alloc = [&](size_t bytes) {
    size_t cur = off;
    off = (off + bytes + 255) & ~(size_t)255;
    return cur;
  };
  int* row_ptr   = (int*)(ws + alloc((NN + 1) * 4));
  float* dis     = (float*)(ws + alloc(NN * 4));
  int* part      = (int*)(ws + alloc(256 * 4));
  float* stats   = (float*)(ws + alloc((D1 * 2 + D2 * 2) * 4));
  float* sc1     = (float*)(ws + alloc(D1 * 4));
  float* sh1     = (float*)(ws + alloc(D1 * 4));
  int* cnt2      = (int*)(ws + alloc((size_t)NN * NBUCK * 4));
  int* col       = (int*)(ws + alloc((size_t)NE * 4));
  unsigned short* H1  = (unsigned short*)(ws + alloc((size_t)NN * D1 * 2));
  unsigned short* A1  = (unsigned short*)(ws + alloc((size_t)NN * D1 * 2));
  unsigned short* H2  = (unsigned short*)(ws + alloc((size_t)NN * D2 * 2));
  unsigned short* W1t = (unsigned short*)(ws + alloc((size_t)DIN * D1 * 2));
  unsigned short* W2t = (unsigned short*)(ws + alloc((size_t)D1 * D2 * 2));
  float* stats2 = stats + D1 * 2;

  const int nb = (NN + 255) / 256;           // 196
  const int nbz = (NN * NBUCK + 255) / 256;  // cnt2 zeroing

  // bucketed CSR build (1 atomic/edge in hist)
  k_zero<<<nbz, 256, 0, stream>>>(cnt2, stats);
  k_hist<<<NE / 256, 256, 0, stream>>>(srcv, dstv, cnt2);
  k_scan_partial<<<nb, 256, 0, stream>>>(cnt2, part);
  k_scan_block<<<1, 256, 0, stream>>>(part, nb);
  k_scan_final<<<nb, 256, 0, stream>>>(cnt2, part, row_ptr, dis);
  k_fill<<<NE / 256, 256, 0, stream>>>(srcv, dstv, cnt2, col);

  // weight transpose + bf16 convert
  k_prep_w<<<(DIN * D1 + D1 * D2) / 256, 256, 0, stream>>>(W1, W2, W1t, W2t);

  const int mb = (NN + 127) / 128;  // 391

  // conv1: single-pass-x GEMM, agg, stats (raw A1), finalize scale/shift
  k_gemm1<<<mb, 512, 0, stream>>>(x, W1t, H1, NN);
  k_agg1<<<(NN + 3) / 4, 256, 0, stream>>>(H1, row_ptr, col, dis, b1, A1);
  k_stats1<<<(NN + 63) / 64, 256, 0, stream>>>(A1, stats);
  k_finalize1<<<1, 256, 0, stream>>>(stats, g1, be1, sc1, sh1);

  // conv2: BN1+ReLU fused into A-staging
  k_gemm2<<<mb, 256, 0, stream>>>(A1, sc1, sh1, W2t, H2, NN);
  k_agg2<<<(NN + 3) / 4, 256, 0, stream>>>(H2, row_ptr, col, dis, b2, out);
  k_stats2<<<(NN + 127) / 128, 128, 0, stream>>>(out, stats2);
  k_apply2<<<NN * D2 / 256, 256, 0, stream>>>(out, stats2, g2, be2);
}

// Round 6
// 526.492 us; speedup vs baseline: 6.3592x; 1.2384x over previous
//
#include <hip/hip_runtime.h>
#include <hip/hip_bf16.h>

// GCN encoder: conv1(512->256) -> BN -> ReLU -> conv2(256->128) -> BN
// R6: CSR build rewritten as two-pass LDS counting sort (k_part: 128 dst-range
// buckets, 1 global atomic per (block,bucket); k_build: per-bucket LDS sort by
// (node, src-bucket)). Kills the 3.2M device-scope atomics + 210MB of scattered
// write traffic that made k_hist/k_fill top dispatches (R4/R5: ~68B HBM per
// 4B scattered atomic write). part[] aliases H1 (dead until gemm1).
// Kept from R5: MFMA GEMMs (single-pass-x gemm1; BN1+ReLU fused in gemm2
// staging), bucket-ordered col for agg L2 lockstep, wave-per-node agg.

#define NN 50000
#define NE 1600000
#define DIN 512
#define D1 256
#define D2 128
#define EPSV 1e-5f
#define NBUCK 8     // src buckets (agg lockstep)
#define BSZ 6250    // nodes per src bucket
#define NDB 128     // dst buckets (CSR build)
#define NPB 391     // nodes per dst bucket (128*391 = 50048 >= NN)
#define CAP 16384   // part capacity per dst bucket (mean 12500, >30 sigma)

typedef __attribute__((ext_vector_type(8))) short bf16x8_t;
typedef __attribute__((ext_vector_type(4))) float f32x4_t;

__device__ __forceinline__ float bf2f(unsigned short u) {
  return __uint_as_float(((unsigned int)u) << 16);
}
__device__ __forceinline__ unsigned short f2bf(float f) {
  unsigned int u = __float_as_uint(f);
  u += 0x7fffu + ((u >> 16) & 1u);   // RNE
  return (unsigned short)(u >> 16);
}
__device__ __forceinline__ unsigned int pk2(float a, float b) {
  __hip_bfloat162 h = __float22bfloat162_rn(make_float2(a, b));
  union { __hip_bfloat162 h; unsigned int u; } c;
  c.h = h;
  return c.u;
}

// ---------- CSR build: two-pass LDS counting sort ----------
__global__ void k_zero(int* __restrict__ gcursor, float* __restrict__ stats) {
  int i = blockIdx.x * 256 + threadIdx.x;
  if (i < NDB) gcursor[i] = 0;
  if (i < (D1 * 2 + D2 * 2)) stats[i] = 0.0f;
}

// Pass A: partition edges into 128 dst-range buckets (fixed CAP stride).
// packed word: src (16b) | dst_local (9b, <<16) | src_bucket (3b, <<25)
__global__ __launch_bounds__(256) void k_part(const int* __restrict__ src,
                                              const int* __restrict__ dst,
                                              int* __restrict__ gcursor,
                                              unsigned int* __restrict__ part) {
  __shared__ int hist[NDB];
  __shared__ int curs[NDB];
  const int t = threadIdx.x;
  const int EB = NE / 256;  // 6250 edges per block
  const int e0 = blockIdx.x * EB;
  if (t < NDB) hist[t] = 0;
  __syncthreads();
  for (int i = t; i < EB; i += 256) {
    int d = dst[e0 + i];
    atomicAdd(&hist[d / NPB], 1);
  }
  __syncthreads();
  if (t < NDB) {
    int c = hist[t];
    curs[t] = (c > 0) ? atomicAdd(&gcursor[t], c) : 0;
  }
  __syncthreads();
  for (int i = t; i < EB; i += 256) {
    int s = src[e0 + i];
    int d = dst[e0 + i];
    int b = d / NPB;
    int dl = d - b * NPB;
    int sb = (unsigned)s / BSZ;
    unsigned int w = (unsigned)s | ((unsigned)dl << 16) | ((unsigned)sb << 25);
    int pos = atomicAdd(&curs[b], 1);
    if (pos < CAP) part[(size_t)b * CAP + pos] = w;
  }
}

// exclusive prefix over 128 bucket totals -> ebase
__global__ void k_bscan(const int* __restrict__ gcursor, int* __restrict__ ebase) {
  __shared__ int s[NDB];
  int t = threadIdx.x;  // blockDim = 128
  int v = gcursor[t];
  s[t] = v;
  __syncthreads();
  for (int off = 1; off < NDB; off <<= 1) {
    int a = (t >= off) ? s[t - off] : 0;
    __syncthreads();
    s[t] += a;
    __syncthreads();
  }
  ebase[t] = s[t] - v;
  if (t == NDB - 1) ebase[NDB] = s[t];
}

// Pass B: per dst-bucket LDS counting sort by (node_local, src_bucket).
// Emits row_ptr, dis, and col (bucket-sorted per node, dense 50KB segment).
__global__ __launch_bounds__(256) void k_build(const unsigned int* __restrict__ part,
                                               const int* __restrict__ gcursor,
                                               const int* __restrict__ ebase,
                                               int* __restrict__ row_ptr,
                                               float* __restrict__ dis,
                                               int* __restrict__ col) {
  const int NC = NPB * NBUCK;  // 3128 counters
  __shared__ int cnt[NC];
  __shared__ int tsum[256];
  const int b = blockIdx.x, t = threadIdx.x;
  int m = gcursor[b];
  if (m > CAP) m = CAP;
  const int base = ebase[b];
  const unsigned int* my = part + (size_t)b * CAP;
  for (int i = t; i < NC; i += 256) cnt[i] = 0;
  __syncthreads();
  for (int i = t; i < m; i += 256) {
    unsigned int w = my[i];
    atomicAdd(&cnt[((w >> 16) & 0x1ff) * NBUCK + (w >> 25)], 1);
  }
  __syncthreads();
  // exclusive scan of cnt[0..NC)
  const int CHK = (NC + 255) / 256;  // 13
  int i0 = t * CHK;
  int sum = 0;
  for (int i = 0; i < CHK; i++) {
    int idx = i0 + i;
    if (idx < NC) sum += cnt[idx];
  }
  tsum[t] = sum;
  __syncthreads();
  for (int off = 1; off < 256; off <<= 1) {
    int a = (t >= off) ? tsum[t - off] : 0;
    __syncthreads();
    tsum[t] += a;
    __syncthreads();
  }
  int run = tsum[t] - sum;
  for (int i = 0; i < CHK; i++) {
    int idx = i0 + i;
    if (idx < NC) {
      int c = cnt[idx];
      cnt[idx] = run;
      run += c;
    }
  }
  __syncthreads();
  // row_ptr / dis from scan values
  const int n0 = b * NPB;
  for (int dl = t; dl < NPB; dl += 256) {
    int n = n0 + dl;
    if (n < NN) {
      int st = cnt[dl * NBUCK];
      int en = (dl * NBUCK + NBUCK < NC) ? cnt[dl * NBUCK + NBUCK] : m;
      row_ptr[n] = base + st;
      dis[n] = rsqrtf((float)(en - st + 1));  // +1 self loop
    }
  }
  if (b == NDB - 1 && t == 0) row_ptr[NN] = base + m;
  __syncthreads();
  // scatter (cnt now serves as cursors); col segment [base, base+m) is dense
  for (int i = t; i < m; i += 256) {
    unsigned int w = my[i];
    int pos = atomicAdd(&cnt[((w >> 16) & 0x1ff) * NBUCK + (w >> 25)], 1);
    col[base + pos] = w & 0xffff;
  }
}

// ---------- weight prep: W [KxN] fp32 -> Wt [NxK] bf16 ----------
__global__ void k_prep_w(const float* __restrict__ W1, const float* __restrict__ W2,
                         unsigned short* __restrict__ W1t, unsigned short* __restrict__ W2t) {
  int i = blockIdx.x * 256 + threadIdx.x;
  if (i < DIN * D1) {  // W1t[n*DIN + k] = W1[k*D1 + n]
    int n = i / DIN, k = i - n * DIN;
    W1t[i] = f2bf(W1[(size_t)k * D1 + n]);
  } else {
    int j = i - DIN * D1;  // W2t[n*D1 + k] = W2[k*D2 + n]
    int n = j / D1, k = j - n * D1;
    W2t[j] = f2bf(W2[(size_t)k * D2 + n]);
  }
}

// ---------- GEMM1: H1[M x 256] = x[M x 512] @ W1t[256 x 512]^T ----------
// 512 threads (8 waves), 128M x 256N tile, BK=64. x read ONCE.
__global__ __launch_bounds__(512) void k_gemm1(const float* __restrict__ A,
                                               const unsigned short* __restrict__ Bt,
                                               unsigned short* __restrict__ C, int M) {
  __shared__ unsigned short As[128 * 64];
  __shared__ unsigned short Bs[256 * 64];
  const int t = threadIdx.x;
  const int wave = t >> 6, lane = t & 63;
  const int m0 = blockIdx.x * 128;
  const int wm = (wave & 1) * 64, wn = (wave >> 1) * 64;  // 2x4 wave grid
  const int l8 = lane >> 3;
  const int lbs = (lane & 7) ^ l8;
  const int row_c = lane & 15, quad = lane >> 4;

  f32x4_t acc[4][4];
#pragma unroll
  for (int i = 0; i < 4; i++)
#pragma unroll
    for (int j = 0; j < 4; j++) acc[i][j] = (f32x4_t){0.f, 0.f, 0.f, 0.f};

  for (int k0 = 0; k0 < DIN; k0 += 64) {
#pragma unroll
    for (int j = 0; j < 4; j++) {
      int chunk = wave * 4 + j;
      int row = chunk * 8 + l8;
      const unsigned short* g = Bt + (size_t)row * DIN + k0 + lbs * 8;
      __builtin_amdgcn_global_load_lds(
          (const __attribute__((address_space(1))) unsigned int*)g,
          (__attribute__((address_space(3))) unsigned int*)(Bs + chunk * 512), 16, 0, 0);
    }
#pragma unroll
    for (int i = 0; i < 2; i++) {
      int bid = i * 512 + t;
      int row = bid >> 3, pb = bid & 7;
      int lb = pb ^ (row & 7);
      int gm = m0 + row;
      if (gm >= M) gm = M - 1;
      const float4* s = (const float4*)(A + (size_t)gm * DIN + k0 + lb * 8);
      float4 v0 = s[0], v1 = s[1];
      uint4 o;
      o.x = pk2(v0.x, v0.y);
      o.y = pk2(v0.z, v0.w);
      o.z = pk2(v1.x, v1.y);
      o.w = pk2(v1.z, v1.w);
      *(uint4*)(As + row * 64 + pb * 8) = o;
    }
    __syncthreads();
#pragma unroll
    for (int ki = 0; ki < 2; ki++) {
      bf16x8_t af[4], bfr[4];
      int kb = ki * 4 + quad;
#pragma unroll
      for (int i = 0; i < 4; i++) {
        int ar = wm + i * 16 + row_c;
        af[i] = *(const bf16x8_t*)(As + ar * 64 + ((kb ^ (ar & 7)) * 8));
        int br = wn + i * 16 + row_c;
        bfr[i] = *(const bf16x8_t*)(Bs + br * 64 + ((kb ^ (br & 7)) * 8));
      }
#pragma unroll
      for (int i = 0; i < 4; i++)
#pragma unroll
        for (int j = 0; j < 4; j++)
          acc[i][j] = __builtin_amdgcn_mfma_f32_16x16x32_bf16(af[i], bfr[j], acc[i][j], 0, 0, 0);
    }
    __syncthreads();
  }
#pragma unroll
  for (int i = 0; i < 4; i++) {
#pragma unroll
    for (int j = 0; j < 4; j++) {
      int colv = wn + j * 16 + row_c;
#pragma unroll
      for (int r = 0; r < 4; r++) {
        int gm = m0 + wm + i * 16 + quad * 4 + r;
        if (gm < M) C[(size_t)gm * D1 + colv] = f2bf(acc[i][j][r]);
      }
    }
  }
}

// per-column BN1 scale/shift from stats
__global__ void k_finalize1(const float* __restrict__ stats, const float* __restrict__ gamma,
                            const float* __restrict__ beta, float* __restrict__ sc1,
                            float* __restrict__ sh1) {
  int c = threadIdx.x;  // 256
  float mean = stats[c] * (1.0f / NN);
  float var = stats[D1 + c] * (1.0f / NN) - mean * mean;
  float sc = gamma[c] * rsqrtf(var + EPSV);
  sc1[c] = sc;
  sh1[c] = beta[c] - mean * sc;
}

// ---------- GEMM2: H2[M x 128] = relu(BN(A1))[M x 256] @ W2t[128 x 256]^T ----------
__global__ __launch_bounds__(256) void k_gemm2(const unsigned short* __restrict__ A,
                                               const float* __restrict__ sc1,
                                               const float* __restrict__ sh1,
                                               const unsigned short* __restrict__ Bt,
                                               unsigned short* __restrict__ C, int M) {
  __shared__ unsigned short As[128 * 64];
  __shared__ unsigned short Bs[128 * 64];
  const int t = threadIdx.x;
  const int wave = t >> 6, lane = t & 63;
  const int m0 = blockIdx.x * 128;
  const int wm = (wave >> 1) * 64, wn = (wave & 1) * 64;
  const int l8 = lane >> 3;
  const int lbs = (lane & 7) ^ l8;
  const int row_c = lane & 15, quad = lane >> 4;

  f32x4_t acc[4][4];
#pragma unroll
  for (int i = 0; i < 4; i++)
#pragma unroll
    for (int j = 0; j < 4; j++) acc[i][j] = (f32x4_t){0.f, 0.f, 0.f, 0.f};

  for (int k0 = 0; k0 < D1; k0 += 64) {
#pragma unroll
    for (int j = 0; j < 4; j++) {
      int chunk = wave * 4 + j;
      int row = chunk * 8 + l8;
      const unsigned short* g = Bt + (size_t)row * D1 + k0 + lbs * 8;
      __builtin_amdgcn_global_load_lds(
          (const __attribute__((address_space(1))) unsigned int*)g,
          (__attribute__((address_space(3))) unsigned int*)(Bs + chunk * 512), 16, 0, 0);
    }
#pragma unroll
    for (int i = 0; i < 4; i++) {
      int bid = i * 256 + t;
      int row = bid >> 3, pb = bid & 7;
      int lb = pb ^ (row & 7);
      int gm = m0 + row;
      if (gm >= M) gm = M - 1;
      int colb = k0 + lb * 8;
      uint4 raw = *(const uint4*)(A + (size_t)gm * D1 + colb);
      float4 scA = *(const float4*)(sc1 + colb);
      float4 scB = *(const float4*)(sc1 + colb + 4);
      float4 shA = *(const float4*)(sh1 + colb);
      float4 shB = *(const float4*)(sh1 + colb + 4);
      float f0 = fmaxf(fmaf(bf2f((unsigned short)(raw.x & 0xffff)), scA.x, shA.x), 0.f);
      float f1 = fmaxf(fmaf(bf2f((unsigned short)(raw.x >> 16)),    scA.y, shA.y), 0.f);
      float f2 = fmaxf(fmaf(bf2f((unsigned short)(raw.y & 0xffff)), scA.z, shA.z), 0.f);
      float f3 = fmaxf(fmaf(bf2f((unsigned short)(raw.y >> 16)),    scA.w, shA.w), 0.f);
      float f4 = fmaxf(fmaf(bf2f((unsigned short)(raw.z & 0xffff)), scB.x, shB.x), 0.f);
      float f5 = fmaxf(fmaf(bf2f((unsigned short)(raw.z >> 16)),    scB.y, shB.y), 0.f);
      float f6 = fmaxf(fmaf(bf2f((unsigned short)(raw.w & 0xffff)), scB.z, shB.z), 0.f);
      float f7 = fmaxf(fmaf(bf2f((unsigned short)(raw.w >> 16)),    scB.w, shB.w), 0.f);
      uint4 o;
      o.x = pk2(f0, f1);
      o.y = pk2(f2, f3);
      o.z = pk2(f4, f5);
      o.w = pk2(f6, f7);
      *(uint4*)(As + row * 64 + pb * 8) = o;
    }
    __syncthreads();
#pragma unroll
    for (int ki = 0; ki < 2; ki++) {
      bf16x8_t af[4], bfr[4];
      int kb = ki * 4 + quad;
#pragma unroll
      for (int i = 0; i < 4; i++) {
        int ar = wm + i * 16 + row_c;
        af[i] = *(const bf16x8_t*)(As + ar * 64 + ((kb ^ (ar & 7)) * 8));
        int br = wn + i * 16 + row_c;
        bfr[i] = *(const bf16x8_t*)(Bs + br * 64 + ((kb ^ (br & 7)) * 8));
      }
#pragma unroll
      for (int i = 0; i < 4; i++)
#pragma unroll
        for (int j = 0; j < 4; j++)
          acc[i][j] = __builtin_amdgcn_mfma_f32_16x16x32_bf16(af[i], bfr[j], acc[i][j], 0, 0, 0);
    }
    __syncthreads();
  }
#pragma unroll
  for (int i = 0; i < 4; i++) {
#pragma unroll
    for (int j = 0; j < 4; j++) {
      int colv = wn + j * 16 + row_c;
      if (colv < D2) {
#pragma unroll
        for (int r = 0; r < 4; r++) {
          int gm = m0 + wm + i * 16 + quad * 4 + r;
          if (gm < M) C[(size_t)gm * D2 + colv] = f2bf(acc[i][j][r]);
        }
      }
    }
  }
}

// ---------- CSR aggregation: one wave per node (col is src-bucket-sorted) ----------
__global__ __launch_bounds__(256) void k_agg1(const unsigned short* __restrict__ H,
                                              const int* __restrict__ row_ptr,
                                              const int* __restrict__ col,
                                              const float* __restrict__ dis,
                                              const float* __restrict__ bias,
                                              unsigned short* __restrict__ OUT) {
  int n = blockIdx.x * 4 + (threadIdx.x >> 6);
  int lane = threadIdx.x & 63;
  if (n >= NN) return;
  float dn = dis[n];
  ushort4 v = ((const ushort4*)(H + (size_t)n * D1))[lane];
  float wsf = dn * dn;
  float a0 = wsf * bf2f(v.x), a1 = wsf * bf2f(v.y);
  float a2 = wsf * bf2f(v.z), a3 = wsf * bf2f(v.w);
  int e = row_ptr[n], e1 = row_ptr[n + 1];
  for (; e + 3 < e1; e += 4) {
    int s0 = col[e], s1 = col[e + 1], s2 = col[e + 2], s3 = col[e + 3];
    float w0 = dis[s0] * dn, w1 = dis[s1] * dn;
    float w2 = dis[s2] * dn, w3 = dis[s3] * dn;
    ushort4 u0 = ((const ushort4*)(H + (size_t)s0 * D1))[lane];
    ushort4 u1 = ((const ushort4*)(H + (size_t)s1 * D1))[lane];
    ushort4 u2 = ((const ushort4*)(H + (size_t)s2 * D1))[lane];
    ushort4 u3 = ((const ushort4*)(H + (size_t)s3 * D1))[lane];
    a0 += w0 * bf2f(u0.x) + w1 * bf2f(u1.x) + w2 * bf2f(u2.x) + w3 * bf2f(u3.x);
    a1 += w0 * bf2f(u0.y) + w1 * bf2f(u1.y) + w2 * bf2f(u2.y) + w3 * bf2f(u3.y);
    a2 += w0 * bf2f(u0.z) + w1 * bf2f(u1.z) + w2 * bf2f(u2.z) + w3 * bf2f(u3.z);
    a3 += w0 * bf2f(u0.w) + w1 * bf2f(u1.w) + w2 * bf2f(u2.w) + w3 * bf2f(u3.w);
  }
  for (; e < e1; e++) {
    int sa = col[e];
    float wa = dis[sa] * dn;
    ushort4 ua = ((const ushort4*)(H + (size_t)sa * D1))[lane];
    a0 += wa * bf2f(ua.x);
    a1 += wa * bf2f(ua.y);
    a2 += wa * bf2f(ua.z);
    a3 += wa * bf2f(ua.w);
  }
  int c = lane * 4;
  a0 += bias[c]; a1 += bias[c + 1]; a2 += bias[c + 2]; a3 += bias[c + 3];
  ushort4 o;
  o.x = f2bf(a0); o.y = f2bf(a1); o.z = f2bf(a2); o.w = f2bf(a3);
  ((ushort4*)(OUT + (size_t)n * D1))[lane] = o;
}

__global__ __launch_bounds__(256) void k_agg2(const unsigned short* __restrict__ H,
                                              const int* __restrict__ row_ptr,
                                              const int* __restrict__ col,
                                              const float* __restrict__ dis,
                                              const float* __restrict__ bias,
                                              float* __restrict__ OUT) {
  int n = blockIdx.x * 4 + (threadIdx.x >> 6);
  int lane = threadIdx.x & 63;
  if (n >= NN) return;
  float dn = dis[n];
  ushort2 v = ((const ushort2*)(H + (size_t)n * D2))[lane];
  float wsf = dn * dn;
  float a0 = wsf * bf2f(v.x), a1 = wsf * bf2f(v.y);
  int e = row_ptr[n], e1 = row_ptr[n + 1];
  for (; e + 3 < e1; e += 4) {
    int s0 = col[e], s1 = col[e + 1], s2 = col[e + 2], s3 = col[e + 3];
    float w0 = dis[s0] * dn, w1 = dis[s1] * dn;
    float w2 = dis[s2] * dn, w3 = dis[s3] * dn;
    ushort2 u0 = ((const ushort2*)(H + (size_t)s0 * D2))[lane];
    ushort2 u1 = ((const ushort2*)(H + (size_t)s1 * D2))[lane];
    ushort2 u2 = ((const ushort2*)(H + (size_t)s2 * D2))[lane];
    ushort2 u3 = ((const ushort2*)(H + (size_t)s3 * D2))[lane];
    a0 += w0 * bf2f(u0.x) + w1 * bf2f(u1.x) + w2 * bf2f(u2.x) + w3 * bf2f(u3.x);
    a1 += w0 * bf2f(u0.y) + w1 * bf2f(u1.y) + w2 * bf2f(u2.y) + w3 * bf2f(u3.y);
  }
  for (; e < e1; e++) {
    int sa = col[e];
    float wa = dis[sa] * dn;
    ushort2 ua = ((const ushort2*)(H + (size_t)sa * D2))[lane];
    a0 += wa * bf2f(ua.x);
    a1 += wa * bf2f(ua.y);
  }
  int c = lane * 2;
  a0 += bias[c]; a1 += bias[c + 1];
  ((float2*)(OUT + (size_t)n * D2))[lane] = make_float2(a0, a1);
}

// ---------- BatchNorm stats ----------
__global__ void k_stats1(const unsigned short* __restrict__ X, float* __restrict__ stats) {
  int t = threadIdx.x;  // column 0..255
  int r0 = blockIdx.x * 64;
  int r1 = (r0 + 64 < NN) ? r0 + 64 : NN;
  float s = 0.f, q = 0.f;
  for (int r = r0; r < r1; r++) {
    float v = bf2f(X[(size_t)r * D1 + t]);
    s += v;
    q += v * v;
  }
  atomicAdd(&stats[t], s);
  atomicAdd(&stats[D1 + t], q);
}

__global__ void k_stats2(const float* __restrict__ X, float* __restrict__ stats) {
  int t = threadIdx.x;  // column 0..127
  int r0 = blockIdx.x * 128;
  int r1 = (r0 + 128 < NN) ? r0 + 128 : NN;
  float s = 0.f, q = 0.f;
  for (int r = r0; r < r1; r++) {
    float v = X[(size_t)r * D2 + t];
    s += v;
    q += v * v;
  }
  atomicAdd(&stats[t], s);
  atomicAdd(&stats[D2 + t], q);
}

__global__ void k_apply2(float* __restrict__ X, const float* __restrict__ stats,
                         const float* __restrict__ gamma, const float* __restrict__ beta) {
  int i = blockIdx.x * blockDim.x + threadIdx.x;
  int c = i & (D2 - 1);
  float mean = stats[c] * (1.0f / NN);
  float var = stats[D2 + c] * (1.0f / NN) - mean * mean;
  float sc = gamma[c] * rsqrtf(var + EPSV);
  X[i] = (X[i] - mean) * sc + beta[c];
}

extern "C" void kernel_launch(void* const* d_in, const int* in_sizes, int n_in,
                              void* d_out, int out_size, void* d_ws, size_t ws_size,
                              hipStream_t stream) {
  const float* x  = (const float*)d_in[0];
  const int* ei   = (const int*)d_in[1];  // [2, NE], int32
  const int* srcv = ei;
  const int* dstv = ei + NE;
  const float* W1  = (const float*)d_in[2];
  const float* b1  = (const float*)d_in[3];
  const float* g1  = (const float*)d_in[4];
  const float* be1 = (const float*)d_in[5];
  const float* W2  = (const float*)d_in[6];
  const float* b2  = (const float*)d_in[7];
  const float* g2  = (const float*)d_in[8];
  const float* be2 = (const float*)d_in[9];
  float* out = (float*)d_out;

  char* ws = (char*)d_ws;
  size_t off = 0;
  auto alloc = [&](size_t bytes) {
    size_t cur = off;
    off = (off + bytes + 255) & ~(size_t)255;
    return cur;
  };
  int* row_ptr   = (int*)(ws + alloc((NN + 1) * 4));
  float* dis     = (float*)(ws + alloc(NN * 4));
  int* gcursor   = (int*)(ws + alloc(NDB * 4));
  int* ebase     = (int*)(ws + alloc((NDB + 1) * 4));
  float* stats   = (float*)(ws + alloc((D1 * 2 + D2 * 2) * 4));
  float* sc1     = (float*)(ws + alloc(D1 * 4));
  float* sh1     = (float*)(ws + alloc(D1 * 4));
  int* col       = (int*)(ws + alloc((size_t)NE * 4));
  unsigned short* H1  = (unsigned short*)(ws + alloc((size_t)NN * D1 * 2));
  unsigned short* A1  = (unsigned short*)(ws + alloc((size_t)NN * D1 * 2));
  unsigned short* H2  = (unsigned short*)(ws + alloc((size_t)NN * D2 * 2));
  unsigned short* W1t = (unsigned short*)(ws + alloc((size_t)DIN * D1 * 2));
  unsigned short* W2t = (unsigned short*)(ws + alloc((size_t)D1 * D2 * 2));
  float* stats2 = stats + D1 * 2;
  // part aliases H1 (dead until k_gemm1; 8.4 MB <= 25.6 MB)
  unsigned int* part = (unsigned int*)H1;

  // CSR build: partition -> bucket scan -> per-bucket counting sort
  k_zero<<<3, 256, 0, stream>>>(gcursor, stats);
  k_part<<<256, 256, 0, stream>>>(srcv, dstv, gcursor, part);
  k_bscan<<<1, NDB, 0, stream>>>(gcursor, ebase);
  k_build<<<NDB, 256, 0, stream>>>(part, gcursor, ebase, row_ptr, dis, col);

  // weight transpose + bf16 convert
  k_prep_w<<<(DIN * D1 + D1 * D2) / 256, 256, 0, stream>>>(W1, W2, W1t, W2t);

  const int mb = (NN + 127) / 128;  // 391

  // conv1
  k_gemm1<<<mb, 512, 0, stream>>>(x, W1t, H1, NN);
  k_agg1<<<(NN + 3) / 4, 256, 0, stream>>>(H1, row_ptr, col, dis, b1, A1);
  k_stats1<<<(NN + 63) / 64, 256, 0, stream>>>(A1, stats);
  k_finalize1<<<1, 256, 0, stream>>>(stats, g1, be1, sc1, sh1);

  // conv2
  k_gemm2<<<mb, 256, 0, stream>>>(A1, sc1, sh1, W2t, H2, NN);
  k_agg2<<<(NN + 3) / 4, 256, 0, stream>>>(H2, row_ptr, col, dis, b2, out);
  k_stats2<<<(NN + 127) / 128, 128, 0, stream>>>(out, stats2);
  k_apply2<<<NN * D2 / 256, 256, 0, stream>>>(out, stats2, g2, be2);
}